// Round 10
// baseline (438.208 us; speedup 1.0000x reference)
//
#include <hip/hip_runtime.h>
#include <hip/hip_bf16.h>
#include <stdint.h>

// ---------- types ----------
typedef __bf16 bf16x8 __attribute__((ext_vector_type(8)));
typedef float  f32x16 __attribute__((ext_vector_type(16)));
typedef unsigned short u16x8 __attribute__((ext_vector_type(8)));
typedef unsigned short u16x4 __attribute__((ext_vector_type(4)));
typedef _Float16 f16x4 __attribute__((ext_vector_type(4)));

#define HS    1024     // hidden size
#define FOURH 4096
#define SEQ   512
#define BATCH 64

#define BAR()  asm volatile("s_barrier" ::: "memory")
#define VMW(n) asm volatile("s_waitcnt vmcnt(" #n ")" ::: "memory")

// manual round-to-nearest-even f32 -> bf16 bits
__device__ __forceinline__ unsigned short f2bf(float f) {
    unsigned u = __builtin_bit_cast(unsigned, f);
    u = (u + 0x7FFFu + ((u >> 16) & 1u)) >> 16;
    return (unsigned short)u;
}

__device__ __forceinline__ void gload_lds16(const void* g, void* l) {
    __builtin_amdgcn_global_load_lds(
        (const __attribute__((address_space(1))) void*)g,
        (__attribute__((address_space(3))) void*)l, 16, 0, 0);
}

__device__ __forceinline__ float fsigmoid(float v) {
    return __builtin_amdgcn_rcpf(1.f + __expf(-v));
}
__device__ __forceinline__ float ftanh(float v) {
    return 1.f - 2.f * __builtin_amdgcn_rcpf(1.f + __expf(2.f * v));
}

// ---------- kernel 1: x (f32) -> Xb (bf16) ----------
__global__ __launch_bounds__(256) void convert_x(const float* __restrict__ x,
                                                 unsigned short* __restrict__ xb,
                                                 long n8) {
    long i = (long)blockIdx.x * blockDim.x + threadIdx.x;
    long stride = (long)gridDim.x * blockDim.x;
    for (; i < n8; i += stride) {
        const float4* p = (const float4*)(x + i * 8);
        float4 a = p[0], b = p[1];
        u16x8 o;
        o[0] = f2bf(a.x); o[1] = f2bf(a.y); o[2] = f2bf(a.z); o[3] = f2bf(a.w);
        o[4] = f2bf(b.x); o[5] = f2bf(b.y); o[6] = f2bf(b.z); o[7] = f2bf(b.w);
        *(u16x8*)(xb + i * 8) = o;
    }
}

// ---------- kernel 2: U [1024][4096] f32 -> Ut [4096][1024] bf16 ----------
__global__ __launch_bounds__(256) void transpose_u(const float* __restrict__ U,
                                                   unsigned short* __restrict__ Ut) {
    __shared__ float tile[32][33];
    int bx = blockIdx.x;            // 4096 blocks
    int tn = bx >> 5;               // n tile
    int tk = bx & 31;               // k tile
    int c = threadIdx.x & 31;
    int r = threadIdx.x >> 5;
#pragma unroll
    for (int i = 0; i < 4; ++i) {
        int k = tk * 32 + r + i * 8;
        tile[r + i * 8][c] = U[(size_t)k * FOURH + tn * 32 + c];
    }
    __syncthreads();
#pragma unroll
    for (int i = 0; i < 4; ++i) {
        int nl = r + i * 8;
        Ut[(size_t)(tn * 32 + nl) * HS + tk * 32 + c] = f2bf(tile[c][nl]);
    }
}

// ---------- kernel 3: 256x256, BK=64, 32x32x16 MFMA, r8 schedule --------------
// 8 waves (2M x 4N), per-wave 128x64 = 4x2 frags of 32x32. LDS: [32r][16k]
// subtiles of 1KB; slot-swizzle k8 ^= (row>>2)&1 -> conflict-free b128 reads
// (pre-swizzled global source, linear gload_lds dest). Consumption: R1 needs
// A-subtiles {0,1,4,5}+all B (6 slots), R2 needs A{2,3,6,7} (2 slots); stage
// order matches; VMW(6) mid-tile, VMW(2) boundary. Queue 2..8, never drains.
__global__ __launch_bounds__(512, 1) void gemm_gates8(
    const unsigned short* __restrict__ Xb,   // [B*S][1024] bf16
    const unsigned short* __restrict__ Ut,   // [4096][1024] bf16
    const float* __restrict__ bias,          // [4096]
    _Float16* __restrict__ gates,            // packed [BATCH*chunk/4][4096][4]
    int lg2chunk, int s0) {
    __shared__ unsigned short LDSU[65536];   // 128KB: buf(t&1)*32768; A@0, B@+16384

    // T1: XCD-aware block swizzle (nwg multiple of 8)
    int nwg = gridDim.x;
    int bid = blockIdx.x;
    int wg = (bid & 7) * (nwg >> 3) + (bid >> 3);
    int mt = wg >> 4;            // 16 n-tiles (4096/256)
    int nt = wg & 15;

    int tid = threadIdx.x;
    int w = tid >> 6, l = tid & 63;
    int wr = w >> 2, wc = w & 3;       // wave grid 2 (M) x 4 (N)
    int l31 = l & 31, lhi = l >> 5;

    const int m0 = mt * 256, n0 = nt * 256;
    const int cmask = (1 << lg2chunk) - 1;

    // read offset within a [32r][16k] subtile (ushort units), slot-swizzled
    const int ro = l31 * 16 + ((lhi ^ ((l31 >> 2) & 1)) << 3);

    // staging: lane l covers subtile row l>>1, stored slot l&1 which holds
    // k8_src = (l&1) ^ ((l>>3)&1)  [slot = k8 ^ ((row>>2)&1), row = l>>1]
    const int k8src = ((l & 1) ^ ((l >> 3) & 1)) * 8;

    // A staged in two groups: R1-needs ms {0,1,4,5}, R2-needs ms {2,3,6,7}.
    // wave pair (w>>1) owns one ms per group; ks covered = (w&1) + 2*s.
    const int msR1 = (w >> 1) + ((w >> 2) << 1);   // {0,1,4,5}[w>>1]
    const int msR2 = msR1 + 2;
    const int ksw = (w & 1);

    auto mkA = [&](int ms) {
        int mrow = m0 + ms * 32 + (l >> 1);
        int b = mrow >> lg2chunk, sl2 = mrow & cmask;
        return Xb + (size_t)(b * SEQ + s0 + sl2) * HS + k8src;
    };
    const unsigned short* pA1 = mkA(msR1);
    const unsigned short* pA2 = mkA(msR2);
    const unsigned short* pB  = Ut + (size_t)(n0 + w * 32 + (l >> 1)) * HS + k8src;

    f32x16 acc[4][2];
#pragma unroll
    for (int mi = 0; mi < 4; ++mi)
#pragma unroll
        for (int ni = 0; ni < 2; ++ni) acc[mi][ni] = 0.f;

#define SA1(T, S) gload_lds16(pA1 + (T) * 64 + (ksw + 2 * (S)) * 16, \
        &LDSU[(((T) & 1) << 15) + (msR1 * 4 + ksw + 2 * (S)) * 512])
#define SA2(T, S) gload_lds16(pA2 + (T) * 64 + (ksw + 2 * (S)) * 16, \
        &LDSU[(((T) & 1) << 15) + (msR2 * 4 + ksw + 2 * (S)) * 512])
#define SBS(T, S) gload_lds16(pB + (T) * 64 + (S) * 16, \
        &LDSU[(((T) & 1) << 15) + 16384 + (w * 4 + (S)) * 512])

    bf16x8 av[2][4], bv_[2][4];

#define RDA(MH) \
    _Pragma("unroll") for (int ks = 0; ks < 4; ++ks) \
    _Pragma("unroll") for (int mi = 0; mi < 2; ++mi) \
        av[mi][ks] = *(const bf16x8*)(buf + ((wr * 4 + (MH) * 2 + mi) * 4 + ks) * 512 + ro)
#define RDB() \
    _Pragma("unroll") for (int ks = 0; ks < 4; ++ks) \
    _Pragma("unroll") for (int ni = 0; ni < 2; ++ni) \
        bv_[ni][ks] = *(const bf16x8*)(buf + 16384 + ((wc * 2 + ni) * 4 + ks) * 512 + ro)
#define MMQ(MH) \
    __builtin_amdgcn_s_setprio(1); \
    _Pragma("unroll") for (int ks = 0; ks < 4; ++ks) \
    _Pragma("unroll") for (int mi = 0; mi < 2; ++mi) \
    _Pragma("unroll") for (int ni = 0; ni < 2; ++ni) \
        acc[(MH) * 2 + mi][ni] = __builtin_amdgcn_mfma_f32_32x32x16_bf16( \
            av[mi][ks], bv_[ni][ks], acc[(MH) * 2 + mi][ni], 0, 0, 0); \
    __builtin_amdgcn_s_setprio(0)

    // prologue: stage tile 0, R1-needs first (6 slots), then R2-needs (2)
    SA1(0, 0); SA1(0, 1); SBS(0, 0); SBS(0, 1); SBS(0, 2); SBS(0, 3);
    SA2(0, 0); SA2(0, 1);
    VMW(2); BAR();

    for (int t = 0; t < 16; ++t) {
        const unsigned short* buf = &LDSU[(t & 1) << 15];
        // ---- region 1: Mfrags 0-1 x all N x K; stage all R1-needs of t+1 ----
        RDA(0);
        RDB();
        if (t < 15) { SA1(t + 1, 0); SA1(t + 1, 1);
                      SBS(t + 1, 0); SBS(t + 1, 1); SBS(t + 1, 2); SBS(t + 1, 3); }
        MMQ(0);
        if (t < 15) { VMW(6); } else { VMW(0); }
        BAR();
        // ---- region 2: Mfrags 2-3; stage R2-needs of t+1 ----
        RDA(1);
        if (t < 15) { SA2(t + 1, 0); SA2(t + 1, 1); }
        MMQ(1);
        if (t < 15) { VMW(2); }
        BAR();
    }

    // ---- epilogue: bias + act, direct packed f16x4 stores ----
    // C/D map (32x32): col = lane&31, row = (reg&3) + 8*(reg>>2) + 4*(lane>>5)
    // -> regs 4j..4j+3 are 4 consecutive M-rows (timesteps).
#pragma unroll
    for (int ni = 0; ni < 2; ++ni) {
        int gcol = n0 + wc * 64 + ni * 32 + l31;
        bool is_g = ((gcol >> 10) == 2);
        float bv = bias[gcol];
#pragma unroll
        for (int mi = 0; mi < 4; ++mi) {
            int rgb = ((m0 + wr * 128 + mi * 32) >> 2) + lhi;
#pragma unroll
            for (int j = 0; j < 4; ++j) {
                u16x4 pk;
#pragma unroll
                for (int r = 0; r < 4; ++r) {
                    float v = acc[mi][ni][j * 4 + r] + bv;
                    float e = is_g ? ftanh(v) : fsigmoid(v);
                    pk[r] = __builtin_bit_cast(unsigned short, (_Float16)e);
                }
                *(u16x4*)(gates + ((size_t)(rgb + 2 * j) * FOURH + gcol) * 4) = pk;
            }
        }
    }
#undef SA1
#undef SA2
#undef SBS
#undef RDA
#undef RDB
#undef MMQ
}

// ---------- kernel 4: recurrence on packed gates, one thread per (b,h) -------
__global__ __launch_bounds__(256) void lstm_recur(
    const _Float16* __restrict__ gates,  // packed [rows/4][4096][4] activated
    float* __restrict__ out,             // d_out base (f32)
    float* __restrict__ cstate,          // [65536]
    int chunk, int s0) {
    int t = blockIdx.x * 256 + threadIdx.x;  // 0..65535
    int b = t >> 10, h = t & 1023;
    float c = (s0 == 0) ? 0.f : cstate[t];
    const _Float16* gp = gates + ((size_t)((b * chunk) >> 2) * FOURH + h) * 4;
    float* op = out + (size_t)(b * SEQ + s0) * HS + h;
    float hv = 0.f;
    const int ng = chunk >> 2;               // row-groups of 4 steps
    for (int g4 = 0; g4 < ng; g4 += 2) {
        f16x4 iv[2], fv[2], gv[2], ov[2];
#pragma unroll
        for (int u = 0; u < 2; ++u) {
            const _Float16* q = gp + (size_t)(g4 + u) * (FOURH * 4);
            iv[u] = *(const f16x4*)(q);
            fv[u] = *(const f16x4*)(q + 4096);
            gv[u] = *(const f16x4*)(q + 8192);
            ov[u] = *(const f16x4*)(q + 12288);
        }
#pragma unroll
        for (int u = 0; u < 2; ++u) {
#pragma unroll
            for (int r = 0; r < 4; ++r) {
                c = (float)fv[u][r] * c + (float)iv[u][r] * (float)gv[u][r];
                float th = ftanh(c);
                hv = (float)ov[u][r] * th;
                op[(size_t)((g4 + u) * 4 + r) * HS] = hv;
            }
        }
    }
    cstate[t] = c;
    if (s0 + chunk == SEQ) {
        out[(size_t)BATCH * SEQ * HS + t] = hv;                      // h_T
        out[(size_t)BATCH * SEQ * HS + BATCH * HS + t] = c;          // c_T
    }
}

// ---------- launcher ----------
extern "C" void kernel_launch(void* const* d_in, const int* in_sizes, int n_in,
                              void* d_out, int out_size, void* d_ws, size_t ws_size,
                              hipStream_t stream) {
    const float* x    = (const float*)d_in[0];
    const float* U    = (const float*)d_in[1];
    const float* bias = (const float*)d_in[2];
    float* out = (float*)d_out;
    char*  ws  = (char*)d_ws;

    // ws layout
    unsigned short* Xb = (unsigned short*)ws;                   // 64MB  bf16 x
    unsigned short* Ut = (unsigned short*)(ws + 67108864);      // 8MB   bf16 U^T
    float* cstate      = (float*)(ws + 75497472);               // 256KB
    _Float16* gates    = (_Float16*)(ws + 75759616);            // chunk*0.5MB
    const size_t fixed = 75759616;

    int chunk = 512;
    while (chunk > 4 && fixed + (size_t)BATCH * chunk * FOURH * 2 > ws_size)
        chunk >>= 1;
    int lg2 = 31 - __builtin_clz(chunk);

    convert_x<<<2048, 256, 0, stream>>>(x, Xb, (long)BATCH * SEQ * HS / 8);
    transpose_u<<<4096, 256, 0, stream>>>(U, Ut);

    for (int s0 = 0; s0 < SEQ; s0 += chunk) {
        int mtiles = (BATCH * chunk) / 256;
        gemm_gates8<<<mtiles * 16, 512, 0, stream>>>(Xb, Ut, bias, gates, lg2, s0);
        lstm_recur<<<256, 256, 0, stream>>>(gates, out, cstate, chunk, s0);
    }
}

// Round 11
// 406.769 us; speedup vs baseline: 1.0773x; 1.0773x over previous
//
#include <hip/hip_runtime.h>
#include <hip/hip_bf16.h>
#include <stdint.h>

// ---------- types ----------
typedef __bf16 bf16x8 __attribute__((ext_vector_type(8)));
typedef float  f32x4  __attribute__((ext_vector_type(4)));
typedef unsigned short u16x8 __attribute__((ext_vector_type(8)));
typedef unsigned short u16x4 __attribute__((ext_vector_type(4)));
typedef _Float16 f16x4 __attribute__((ext_vector_type(4)));

#define HS    1024     // hidden size
#define FOURH 4096
#define SEQ   512
#define BATCH 64

#define BAR()  asm volatile("s_barrier" ::: "memory")
#define VMW(n) asm volatile("s_waitcnt vmcnt(" #n ")" ::: "memory")
#define LGKM0() asm volatile("s_waitcnt lgkmcnt(0)" ::: "memory")

// manual round-to-nearest-even f32 -> bf16 bits
__device__ __forceinline__ unsigned short f2bf(float f) {
    unsigned u = __builtin_bit_cast(unsigned, f);
    u = (u + 0x7FFFu + ((u >> 16) & 1u)) >> 16;
    return (unsigned short)u;
}

__device__ __forceinline__ void gload_lds16(const void* g, void* l) {
    __builtin_amdgcn_global_load_lds(
        (const __attribute__((address_space(1))) void*)g,
        (__attribute__((address_space(3))) void*)l, 16, 0, 0);
}

__device__ __forceinline__ float fsigmoid(float v) {
    return __builtin_amdgcn_rcpf(1.f + __expf(-v));
}
__device__ __forceinline__ float ftanh(float v) {
    return 1.f - 2.f * __builtin_amdgcn_rcpf(1.f + __expf(2.f * v));
}

// ---------- kernel 1: x (f32) -> Xb (bf16) ----------
__global__ __launch_bounds__(256) void convert_x(const float* __restrict__ x,
                                                 unsigned short* __restrict__ xb,
                                                 long n8) {
    long i = (long)blockIdx.x * blockDim.x + threadIdx.x;
    long stride = (long)gridDim.x * blockDim.x;
    for (; i < n8; i += stride) {
        const float4* p = (const float4*)(x + i * 8);
        float4 a = p[0], b = p[1];
        u16x8 o;
        o[0] = f2bf(a.x); o[1] = f2bf(a.y); o[2] = f2bf(a.z); o[3] = f2bf(a.w);
        o[4] = f2bf(b.x); o[5] = f2bf(b.y); o[6] = f2bf(b.z); o[7] = f2bf(b.w);
        *(u16x8*)(xb + i * 8) = o;
    }
}

// ---------- kernel 2: U [1024][4096] f32 -> Ut [4096][1024] bf16 ----------
__global__ __launch_bounds__(256) void transpose_u(const float* __restrict__ U,
                                                   unsigned short* __restrict__ Ut) {
    __shared__ float tile[32][33];
    int bx = blockIdx.x;            // 4096 blocks
    int tn = bx >> 5;               // n tile
    int tk = bx & 31;               // k tile
    int c = threadIdx.x & 31;
    int r = threadIdx.x >> 5;
#pragma unroll
    for (int i = 0; i < 4; ++i) {
        int k = tk * 32 + r + i * 8;
        tile[r + i * 8][c] = U[(size_t)k * FOURH + tn * 32 + c];
    }
    __syncthreads();
#pragma unroll
    for (int i = 0; i < 4; ++i) {
        int nl = r + i * 8;
        Ut[(size_t)(tn * 32 + nl) * HS + tk * 32 + c] = f2bf(tile[c][nl]);
    }
}

// ---------- kernel 3: 256x256, BK=64, m201-style 4-phase, 1 vmcnt/tile -------
// 8 waves (2M x 4N). Per tile: ph1 Q(0,0) [12 ds_read], ph2 Q(0,1) [4],
// ph3 Q(1,1) [8], ph4 Q(1,0) [0; bn0 reg-held]. Stage stream runs ~1.75 tiles
// ahead: tile t stages {A-hi(t+1) | A-lo(t+2) | B-lo(t+2) | B-hi(t+2)}, one
// half-tile (2 loads) per phase. Single VMW(6)+BAR at ph4: retires exactly
// t+1's 8 loads, leaves t+2's 6. LDS layout/swizzle identical to r8 (0-confl).
__global__ __launch_bounds__(512, 1) void gemm_gates8(
    const unsigned short* __restrict__ Xb,   // [B*S][1024] bf16
    const unsigned short* __restrict__ Ut,   // [4096][1024] bf16
    const float* __restrict__ bias,          // [4096]
    _Float16* __restrict__ gates,            // packed [BATCH*chunk/4][4096][4]
    int lg2chunk, int s0) {
    __shared__ unsigned short LDSU[65536];   // 128KB: buf(t&1)*32768; A@0, B@+16384

    // T1: XCD-aware block swizzle (nwg multiple of 8)
    int nwg = gridDim.x;
    int bid = blockIdx.x;
    int wg = (bid & 7) * (nwg >> 3) + (bid >> 3);
    int mt = wg >> 4;            // 16 n-tiles (4096/256)
    int nt = wg & 15;

    int tid = threadIdx.x;
    int w = tid >> 6, l = tid & 63;
    int wr = w >> 2, wc = w & 3;       // wave grid 2 (M) x 4 (N)
    int lr = l & 15, lg = l >> 4;

    const int m0 = mt * 256, n0 = nt * 256;
    const int cmask = (1 << lg2chunk) - 1;

    // ds_read offset within a 16x32 subtile (ushort units), st_16x32 swizzle
    const int rdo = lr * 32 + ((lg * 8) ^ ((lr & 8) << 1));

    // staging lane geometry: lane covers row l>>2 of its subtile, k-octet (l&3)
    const int srow = l >> 2;
    const int skin = ((l & 3) * 8) ^ (((l >> 5) & 1) << 4);

    // A quarters (64 rows each); wave w covers subtile (q*4 + (w>>1), ks=w&1)
    const unsigned short* pAq[4];
#pragma unroll
    for (int q = 0; q < 4; ++q) {
        int rowg = q * 64 + (w >> 1) * 16 + srow;
        int mrow = m0 + rowg;
        int b = mrow >> lg2chunk, sl2 = mrow & cmask;
        pAq[q] = Xb + (size_t)(b * SEQ + s0 + sl2) * HS + (w & 1) * 32 + skin;
    }
    const int dsub = (w >> 1) * 2 + (w & 1);   // subtile slot within quarter

    // B halves aligned with NH-consumption: B-lo row16-blocks {0,1,4,5,8,9,
    // 12,13}, B-hi = +2. Wave w, load j covers row-block rb, ks=w&1.
    const unsigned short* pBL[2];
    const unsigned short* pBH[2];
    int slBL[2], slBH[2];
#pragma unroll
    for (int j = 0; j < 2; ++j) {
        int idx = 4 * j + (w >> 1);
        int rbL = ((idx >> 1) << 2) + (idx & 1);
        int rbH = rbL + 2;
        pBL[j] = Ut + (size_t)(n0 + rbL * 16 + srow) * HS + (w & 1) * 32 + skin;
        pBH[j] = Ut + (size_t)(n0 + rbH * 16 + srow) * HS + (w & 1) * 32 + skin;
        slBL[j] = rbL * 2 + (w & 1);
        slBH[j] = rbH * 2 + (w & 1);
    }

    f32x4 acc[8][4];
#pragma unroll
    for (int mi = 0; mi < 8; ++mi)
#pragma unroll
        for (int ni = 0; ni < 4; ++ni) acc[mi][ni] = 0.f;

#define SA(T, Q) gload_lds16(pAq[Q] + (T) * 64, \
        &LDSU[(((T) & 1) << 15) + ((Q) * 8 + dsub) * 512])
#define SALO(T) { SA(T, 0); SA(T, 2); }
#define SAHI(T) { SA(T, 1); SA(T, 3); }
#define SBLO(T) { gload_lds16(pBL[0] + (T) * 64, \
        &LDSU[(((T) & 1) << 15) + 16384 + slBL[0] * 512]); \
                  gload_lds16(pBL[1] + (T) * 64, \
        &LDSU[(((T) & 1) << 15) + 16384 + slBL[1] * 512]); }
#define SBHI(T) { gload_lds16(pBH[0] + (T) * 64, \
        &LDSU[(((T) & 1) << 15) + 16384 + slBH[0] * 512]); \
                  gload_lds16(pBH[1] + (T) * 64, \
        &LDSU[(((T) & 1) << 15) + 16384 + slBH[1] * 512]); }

    bf16x8 aq[2][4], bn0[2][2], bn1[2][2];

#define RDA(MH) \
    _Pragma("unroll") for (int ks = 0; ks < 2; ++ks) \
    _Pragma("unroll") for (int mi = 0; mi < 4; ++mi) \
        aq[ks][mi] = *(const bf16x8*)(buf + ((wr * 8 + (MH) * 4 + mi) * 2 + ks) * 512 + rdo)
#define RDB(NH, BN) \
    _Pragma("unroll") for (int ks = 0; ks < 2; ++ks) \
    _Pragma("unroll") for (int ni = 0; ni < 2; ++ni) \
        BN[ks][ni] = *(const bf16x8*)(buf + 16384 + ((wc * 4 + (NH) * 2 + ni) * 2 + ks) * 512 + rdo)
#define MMQ(MH, NH, BN) \
    __builtin_amdgcn_s_setprio(1); \
    _Pragma("unroll") for (int ks = 0; ks < 2; ++ks) \
    _Pragma("unroll") for (int mi = 0; mi < 4; ++mi) \
    _Pragma("unroll") for (int ni = 0; ni < 2; ++ni) \
        acc[(MH) * 4 + mi][(NH) * 2 + ni] = __builtin_amdgcn_mfma_f32_16x16x32_bf16( \
            aq[ks][mi], BN[ks][ni], acc[(MH) * 4 + mi][(NH) * 2 + ni], 0, 0, 0); \
    __builtin_amdgcn_s_setprio(0)

    // prologue: tile 0 complete + tile 1's first three half-tiles (14 loads);
    // VMW(6) retires tile 0's 8, leaves t1's 6 -> steady-state invariant.
    SALO(0); SBLO(0); SBHI(0); SAHI(0);
    SALO(1); SBLO(1); SBHI(1);
    VMW(6); BAR();

    for (int t = 0; t < 16; ++t) {
        const unsigned short* buf = &LDSU[(t & 1) << 15];
        // ---- ph1: Q(0,0); stage A-hi(t+1) ----
        RDA(0);
        RDB(0, bn0);
        if (t < 15) SAHI(t + 1);
        asm volatile("s_waitcnt lgkmcnt(8)" ::: "memory");
        BAR(); LGKM0();
        MMQ(0, 0, bn0);
        BAR();
        // ---- ph2: Q(0,1); stage A-lo(t+2) ----
        RDB(1, bn1);
        if (t < 14) SALO(t + 2);
        BAR(); LGKM0();
        MMQ(0, 1, bn1);
        BAR();
        // ---- ph3: Q(1,1); stage B-lo(t+2) ----
        RDA(1);
        if (t < 14) SBLO(t + 2);
        BAR(); LGKM0();
        MMQ(1, 1, bn1);
        BAR();
        // ---- ph4: Q(1,0) from reg-held bn0; stage B-hi(t+2); 1 vmcnt/tile --
        if (t < 14) SBHI(t + 2);
        BAR();
        MMQ(1, 0, bn0);
        if (t < 14) { VMW(6); } else if (t == 14) { VMW(0); }
        BAR();
    }

    // ---- epilogue: bias + act, direct packed f16x4 stores ----
    // C/D map: col = lane&15, row = (lane>>4)*4 + r  ->  the 4 r-values are
    // 4 consecutive M-rows (timesteps). Pack to one 8B store per (mi,ni).
#pragma unroll
    for (int ni = 0; ni < 4; ++ni) {
        int gcol = n0 + wc * 64 + ni * 16 + lr;
        bool is_g = ((gcol >> 10) == 2);
        float bv = bias[gcol];
#pragma unroll
        for (int mi = 0; mi < 8; ++mi) {
            int rg = ((m0 + wr * 128 + mi * 16) >> 2) + lg;   // row-group
            u16x4 pk;
#pragma unroll
            for (int r = 0; r < 4; ++r) {
                float v = acc[mi][ni][r] + bv;
                float e = is_g ? ftanh(v) : fsigmoid(v);
                pk[r] = __builtin_bit_cast(unsigned short, (_Float16)e);
            }
            *(u16x4*)(gates + ((size_t)rg * FOURH + gcol) * 4) = pk;
        }
    }
#undef SA
#undef SALO
#undef SAHI
#undef SBLO
#undef SBHI
#undef RDA
#undef RDB
#undef MMQ
}

// ---------- kernel 4: recurrence on packed gates, one thread per (b,h) -------
__global__ __launch_bounds__(256) void lstm_recur(
    const _Float16* __restrict__ gates,  // packed [rows/4][4096][4] activated
    float* __restrict__ out,             // d_out base (f32)
    float* __restrict__ cstate,          // [65536]
    int chunk, int s0) {
    int t = blockIdx.x * 256 + threadIdx.x;  // 0..65535
    int b = t >> 10, h = t & 1023;
    float c = (s0 == 0) ? 0.f : cstate[t];
    const _Float16* gp = gates + ((size_t)((b * chunk) >> 2) * FOURH + h) * 4;
    float* op = out + (size_t)(b * SEQ + s0) * HS + h;
    float hv = 0.f;
    const int ng = chunk >> 2;               // row-groups of 4 steps
    for (int g4 = 0; g4 < ng; g4 += 2) {
        f16x4 iv[2], fv[2], gv[2], ov[2];
#pragma unroll
        for (int u = 0; u < 2; ++u) {
            const _Float16* q = gp + (size_t)(g4 + u) * (FOURH * 4);
            iv[u] = *(const f16x4*)(q);
            fv[u] = *(const f16x4*)(q + 4096);
            gv[u] = *(const f16x4*)(q + 8192);
            ov[u] = *(const f16x4*)(q + 12288);
        }
#pragma unroll
        for (int u = 0; u < 2; ++u) {
#pragma unroll
            for (int r = 0; r < 4; ++r) {
                c = (float)fv[u][r] * c + (float)iv[u][r] * (float)gv[u][r];
                float th = ftanh(c);
                hv = (float)ov[u][r] * th;
                op[(size_t)((g4 + u) * 4 + r) * HS] = hv;
            }
        }
    }
    cstate[t] = c;
    if (s0 + chunk == SEQ) {
        out[(size_t)BATCH * SEQ * HS + t] = hv;                      // h_T
        out[(size_t)BATCH * SEQ * HS + BATCH * HS + t] = c;          // c_T
    }
}

// ---------- launcher ----------
extern "C" void kernel_launch(void* const* d_in, const int* in_sizes, int n_in,
                              void* d_out, int out_size, void* d_ws, size_t ws_size,
                              hipStream_t stream) {
    const float* x    = (const float*)d_in[0];
    const float* U    = (const float*)d_in[1];
    const float* bias = (const float*)d_in[2];
    float* out = (float*)d_out;
    char*  ws  = (char*)d_ws;

    // ws layout
    unsigned short* Xb = (unsigned short*)ws;                   // 64MB  bf16 x
    unsigned short* Ut = (unsigned short*)(ws + 67108864);      // 8MB   bf16 U^T
    float* cstate      = (float*)(ws + 75497472);               // 256KB
    _Float16* gates    = (_Float16*)(ws + 75759616);            // chunk*0.5MB
    const size_t fixed = 75759616;

    int chunk = 512;
    while (chunk > 4 && fixed + (size_t)BATCH * chunk * FOURH * 2 > ws_size)
        chunk >>= 1;
    int lg2 = 31 - __builtin_clz(chunk);

    convert_x<<<2048, 256, 0, stream>>>(x, Xb, (long)BATCH * SEQ * HS / 8);
    transpose_u<<<4096, 256, 0, stream>>>(U, Ut);

    for (int s0 = 0; s0 < SEQ; s0 += chunk) {
        int mtiles = (BATCH * chunk) / 256;
        gemm_gates8<<<mtiles * 16, 512, 0, stream>>>(Xb, Ut, bias, gates, lg2, s0);
        lstm_recur<<<256, 256, 0, stream>>>(gates, out, cstate, chunk, s0);
    }
}